// Round 5
// baseline (460.134 us; speedup 1.0000x reference)
//
#include <hip/hip_runtime.h>

#define N_ROWS 32768
#define DIM 256
#define K_CODES 1024
#define KA 512    // A' row = [h(256) | l(256)]
#define KB 768    // B' row = [H(256) | L(256) | H(256)]  -> B step offset = t*32 linear
#define OUT_QUANT 8388608  // N_ROWS*DIM; out layout: [quant | loss | encodings]

typedef unsigned long long ull;
typedef _Float16 f16;
typedef __attribute__((ext_vector_type(4))) _Float16 f16x4;
typedef __attribute__((ext_vector_type(8))) _Float16 f16x8;
typedef __attribute__((ext_vector_type(4))) float f32x4;

#define NB_ZSPLIT 8192
#define NB_ZNORM 2048
#define NB_CSPLIT 256
#define NB_CNORM 64

// ---- fp16 2-way split: h = fp16(x) (self-flushed below 2^-14), l = fp16((x-h)*2^12)
struct HL { f16 h, l; };
__device__ __forceinline__ HL split2(float x) {
  f16 hh = (f16)x;
  if (__builtin_fabsf(x) < 6.103515625e-05f) hh = (f16)0.0f;
  const float r = __fsub_rn(x, (float)hh);  // exact (Sterbenz / bit-subset)
  HL o;
  o.h = hh;
  o.l = (f16)(__fmul_rn(r, 4096.0f));
  return o;
}

// ---- one prep kernel: z-split, z-norms(+keys init), cb-split(+loss zero), cb-norms ----
__global__ __launch_bounds__(256) void prep(
    const float* __restrict__ z, const float* __restrict__ cb,
    f16* __restrict__ Ap, f16* __restrict__ Bp,
    float* __restrict__ rn, float* __restrict__ cn,
    ull* __restrict__ keys, float* __restrict__ out) {
  const int b = blockIdx.x, tid = threadIdx.x;
  if (b < NB_ZSPLIT) {
    // A' row = [h_z(256) | l_z(256)]
    const size_t g = ((size_t)b * 256 + tid) * 4;
    const int row = (int)(g >> 8), k = (int)(g & 255);
    const float4 v = *(const float4*)(z + g);
    const HL s0 = split2(v.x), s1 = split2(v.y), s2 = split2(v.z), s3 = split2(v.w);
    const f16x4 h = {s0.h, s1.h, s2.h, s3.h};
    const f16x4 l = {s0.l, s1.l, s2.l, s3.l};
    f16* arow = Ap + (size_t)row * KA + k;
    *(f16x4*)(arow) = h;
    *(f16x4*)(arow + 256) = l;
  } else if (b < NB_ZSPLIT + NB_ZNORM) {
    // exact numpy pairwise ||z_row||^2: 8 chains/half, stride-8, tree combine
    const int row = (b - NB_ZSPLIT) * 16 + (tid >> 4);
    const int j = tid & 7, half = (tid >> 3) & 1;
    const float* x = z + (size_t)row * DIM + half * 128 + j;
    float r = __fmul_rn(x[0], x[0]);
#pragma unroll
    for (int t = 1; t < 16; ++t) r = __fadd_rn(r, __fmul_rn(x[8 * t], x[8 * t]));
    r = __fadd_rn(r, __shfl_xor(r, 1));
    r = __fadd_rn(r, __shfl_xor(r, 2));
    r = __fadd_rn(r, __shfl_xor(r, 4));
    const float o = __shfl_xor(r, 8);
    if ((tid & 15) == 0) {
      rn[row] = __fadd_rn(r, o);
      keys[row] = ~0ull;
    }
  } else if (b < NB_ZSPLIT + NB_ZNORM + NB_CSPLIT) {
    // B' row = [H | L | H], e pre-scaled by 2^10
    const int b2 = b - (NB_ZSPLIT + NB_ZNORM);
    const size_t g = ((size_t)b2 * 256 + tid) * 4;
    const int row = (int)(g >> 8), k = (int)(g & 255);
    const float4 v = *(const float4*)(cb + g);
    const HL s0 = split2(__fmul_rn(v.x, 1024.0f));
    const HL s1 = split2(__fmul_rn(v.y, 1024.0f));
    const HL s2 = split2(__fmul_rn(v.z, 1024.0f));
    const HL s3 = split2(__fmul_rn(v.w, 1024.0f));
    const f16x4 h = {s0.h, s1.h, s2.h, s3.h};
    const f16x4 l = {s0.l, s1.l, s2.l, s3.l};
    f16* brow = Bp + (size_t)row * KB + k;
    *(f16x4*)(brow) = h;
    *(f16x4*)(brow + 256) = l;
    *(f16x4*)(brow + 512) = h;
    if (b2 == 0 && tid == 0) out[OUT_QUANT] = 0.0f;
  } else {
    const int row = (b - (NB_ZSPLIT + NB_ZNORM + NB_CSPLIT)) * 16 + (tid >> 4);
    const int j = tid & 7, half = (tid >> 3) & 1;
    const float* x = cb + (size_t)row * DIM + half * 128 + j;
    float r = __fmul_rn(x[0], x[0]);
#pragma unroll
    for (int t = 1; t < 16; ++t) r = __fadd_rn(r, __fmul_rn(x[8 * t], x[8 * t]));
    r = __fadd_rn(r, __shfl_xor(r, 1));
    r = __fadd_rn(r, __shfl_xor(r, 2));
    r = __fadd_rn(r, __shfl_xor(r, 4));
    const float o = __shfl_xor(r, 8);
    if ((tid & 15) == 0) cn[row] = __fadd_rn(r, o);
  }
}

// ---------- barrier-free direct-to-register MFMA GEMM + fused argmin ----------
// one wave = one 64x64 output tile; no LDS, no __syncthreads, depth-2 reg prefetch
__device__ __forceinline__ ull shflx64(ull v, int m) {
  int lo = __shfl_xor((int)(v & 0xffffffffull), m);
  int hi = __shfl_xor((int)(v >> 32), m);
  return ((ull)(unsigned int)hi << 32) | (unsigned int)lo;
}

__global__ __launch_bounds__(256) void gemm_argmin_f16(
    const f16* __restrict__ Ap, const f16* __restrict__ Bp,
    const float* __restrict__ rn, const float* __restrict__ cn,
    ull* __restrict__ keys) {
  const int tid = threadIdx.x, w = tid >> 6, lane = tid & 63;
  const int lq = lane >> 4, lr = lane & 15;
  const int b = blockIdx.x;
  const int xcd = b & 7, i = b >> 3;
  const int mtile = xcd * 64 + (i >> 2);   // A panel pinned to one XCD's L2
  const int ntile = (i & 3) * 4 + w;       // 4 waves of a block share mtile (A in L1)
  const int row0 = mtile * 64, col0 = ntile * 64;

  const f16* aR[4];
  const f16* bR[4];
#pragma unroll
  for (int f = 0; f < 4; ++f) {
    aR[f] = Ap + (size_t)(row0 + f * 16 + lr) * KA + lq * 8;
    bR[f] = Bp + (size_t)(col0 + f * 16 + lr) * KB + lq * 8;
  }

  f32x4 acc[4][4];
#pragma unroll
  for (int a = 0; a < 4; ++a)
#pragma unroll
    for (int c = 0; c < 4; ++c) acc[a][c] = (f32x4){0.f, 0.f, 0.f, 0.f};

  f16x8 av[3][4], bv[3][4];  // 3-slot rotation, all indices compile-time (full unroll)
#pragma unroll
  for (int p = 0; p < 2; ++p) {
    const int ao = (p < 8 ? p : p - 8) * 32, bo = p * 32;
#pragma unroll
    for (int f = 0; f < 4; ++f) {
      av[p][f] = *(const f16x8*)(aR[f] + ao);
      bv[p][f] = *(const f16x8*)(bR[f] + bo);
    }
  }

#pragma unroll
  for (int t = 0; t < 24; ++t) {
    const int cur = t % 3;
    if (t < 22) {
      const int nxt = (t + 2) % 3, tt = t + 2;
      const int ao = (tt < 8 ? tt : tt - 8) * 32, bo = tt * 32;
#pragma unroll
      for (int f = 0; f < 4; ++f) {
        av[nxt][f] = *(const f16x8*)(aR[f] + ao);
        bv[nxt][f] = *(const f16x8*)(bR[f] + bo);
      }
    }
    if (t == 8) {  // h.H chunk (scale 2^10) -> 2^22 before residual chunks
#pragma unroll
      for (int a = 0; a < 4; ++a)
#pragma unroll
        for (int c = 0; c < 4; ++c) acc[a][c] *= 4096.0f;
    }
#pragma unroll
    for (int fm = 0; fm < 4; ++fm)
#pragma unroll
      for (int fn = 0; fn < 4; ++fn)
        acc[fm][fn] = __builtin_amdgcn_mfma_f32_16x16x32_f16(av[cur][fm], bv[cur][fn],
                                                             acc[fm][fn], 0, 0, 0);
  }

  // epilogue: dist = fp32((rn+cn) - acc*2^-21); argmin, first-index ties
  float cnv[4];
#pragma unroll
  for (int fn = 0; fn < 4; ++fn) cnv[fn] = cn[col0 + fn * 16 + lr];

#pragma unroll
  for (int fm = 0; fm < 4; ++fm) {
#pragma unroll
    for (int j = 0; j < 4; ++j) {
      const int rg = row0 + fm * 16 + lq * 4 + j;
      const float a_rn = rn[rg];
      ull best = ~0ull;
#pragma unroll
      for (int fn = 0; fn < 4; ++fn) {
        const int cg = col0 + fn * 16 + lr;
        const float d = __fsub_rn(__fadd_rn(a_rn, cnv[fn]),
                                  __fmul_rn(acc[fm][fn][j], 4.76837158203125e-07f));
        unsigned int mono = __float_as_uint(d);
        mono = (mono & 0x80000000u) ? ~mono : (mono | 0x80000000u);
        const ull key = ((ull)mono << 32) | (unsigned int)cg;
        if (key < best) best = key;
      }
#pragma unroll
      for (int off = 1; off <= 8; off <<= 1) {
        ull o = shflx64(best, off);
        if (o < best) best = o;
      }
      if (lr == 0) atomicMin(&keys[rg], best);
    }
  }
}

// ---------- outputs: quantized, full one-hot rows, loss via atomicAdd ----------
__global__ __launch_bounds__(256) void quantize_out(
    const float* __restrict__ z, const float* __restrict__ cb,
    const ull* __restrict__ keys, float* __restrict__ out) {
  __shared__ float ls[4];
  const int wid = threadIdx.x >> 6, lane = threadIdx.x & 63;
  const int row = blockIdx.x * 4 + wid;
  const int idx = (int)(keys[row] & 0xffffffffull);
  const float4 zv = *(const float4*)(z + (size_t)row * DIM + lane * 4);
  const float4 qv = *(const float4*)(cb + (size_t)idx * DIM + lane * 4);
  const float dx = __fsub_rn(qv.x, zv.x);
  const float dy = __fsub_rn(qv.y, zv.y);
  const float dzz = __fsub_rn(qv.z, zv.z);
  const float dw = __fsub_rn(qv.w, zv.w);
  float4 ov;
  ov.x = __fadd_rn(zv.x, dx); ov.y = __fadd_rn(zv.y, dy);
  ov.z = __fadd_rn(zv.z, dzz); ov.w = __fadd_rn(zv.w, dw);
  *(float4*)(out + (size_t)row * DIM + lane * 4) = ov;
  float s = dx * dx + dy * dy + dzz * dzz + dw * dw;
#pragma unroll
  for (int o = 32; o > 0; o >>= 1) s += __shfl_down(s, o);
  if (lane == 0) ls[wid] = s;

  // full one-hot row (no separate memset)
  float4* enc4 = (float4*)(out + (size_t)OUT_QUANT + 1 + (size_t)row * K_CODES);
  const int target = idx >> 2, comp = idx & 3;
#pragma unroll
  for (int i = 0; i < 4; ++i) {
    const int f4i = lane + 64 * i;
    float4 v = {0.f, 0.f, 0.f, 0.f};
    if (f4i == target) ((float*)&v)[comp] = 1.0f;
    enc4[f4i] = v;
  }

  __syncthreads();
  if (threadIdx.x == 0)
    atomicAdd(out + OUT_QUANT, (ls[0] + ls[1] + ls[2] + ls[3]) * (1.25f / 8388608.0f));
}

extern "C" void kernel_launch(void* const* d_in, const int* in_sizes, int n_in,
                              void* d_out, int out_size, void* d_ws, size_t ws_size,
                              hipStream_t stream) {
  const float* z = (const float*)d_in[0];
  const float* cb = (const float*)d_in[1];
  float* out = (float*)d_out;

  // ws: keys u64[32768] @0 | rn @256K | cn @384K | Ap @512K (32MB) | Bp @512K+32M (1.5MB)
  char* w = (char*)d_ws;
  ull* keys = (ull*)w;
  float* rn = (float*)(w + (256u << 10));
  float* cn = (float*)(w + (384u << 10));
  f16* Ap = (f16*)(w + (512u << 10));
  f16* Bp = (f16*)(w + (512u << 10) + (32u << 20));

  prep<<<NB_ZSPLIT + NB_ZNORM + NB_CSPLIT + NB_CNORM, 256, 0, stream>>>(
      z, cb, Ap, Bp, rn, cn, keys, out);
  gemm_argmin_f16<<<2048, 256, 0, stream>>>(Ap, Bp, rn, cn, keys);
  quantize_out<<<N_ROWS / 4, 256, 0, stream>>>(z, cb, keys, out);
}